// Round 1
// baseline (15910.585 us; speedup 1.0000x reference)
//
#include <hip/hip_runtime.h>
#include <hip/hip_bf16.h>
#include <cstdint>
#include <cstddef>

typedef short short8 __attribute__((ext_vector_type(8)));
typedef float f32x4 __attribute__((ext_vector_type(4)));

#define TT 512
#define BB 64
#define DD 1024
#define LL 1024
#define KTOT 2048

// ---------------------------------------------------------------------------
// Prep: transpose + convert the 4 gate weight matrices [2048,1024] fp32 into
// Wt[c][k] bf16 with c = g*1024 + l (row-major, k contiguous) so the step
// kernel's B-fragments are 16B-contiguous LDS loads.
// grid (64 k-tiles, 32 l-tiles, 4 gates), 256 thr, 32x32 LDS tile transpose.
// ---------------------------------------------------------------------------
__global__ __launch_bounds__(256) void transpose_w(
    const float* __restrict__ Wf, const float* __restrict__ Wi,
    const float* __restrict__ Wo, const float* __restrict__ Wg,
    __hip_bfloat16* __restrict__ Wt) {
  __shared__ float tile[32][33];
  const int g = blockIdx.z;
  const float* W = (g == 0) ? Wf : (g == 1) ? Wi : (g == 2) ? Wo : Wg;
  const int k0 = blockIdx.x * 32, l0 = blockIdx.y * 32;
  const int c = threadIdx.x & 31, r0 = threadIdx.x >> 5;
#pragma unroll
  for (int rr = 0; rr < 4; ++rr) {
    const int kk = r0 + rr * 8;
    tile[kk][c] = W[(size_t)(k0 + kk) * LL + (l0 + c)];  // coalesced along l
  }
  __syncthreads();
#pragma unroll
  for (int rr = 0; rr < 4; ++rr) {
    const int ll = r0 + rr * 8;
    // write coalesced along k
    Wt[((size_t)(g * LL + l0 + ll) << 11) + (k0 + c)] = __float2bfloat16(tile[c][ll]);
  }
}

// ---------------------------------------------------------------------------
// One LSTM step. grid 128 blocks x 256 thr (4 waves).
// Block: all 64 batches x latent tile of 8 (x 4 gates = 32 gate cols).
// K=2048 split over the 4 waves (wave w handles 32-k step w within each
// contiguous 128-k chunk), MFMA 16x16x32 bf16, full-tile partial acc per
// wave, LDS reduction, then fp32 pointwise c/h update (block-local).
// h history is stored in `outp` (out[t] == h_t); step t reads out[t-1].
// ---------------------------------------------------------------------------
__global__ __launch_bounds__(256) void lstm_step(
    const float* __restrict__ x, const __hip_bfloat16* __restrict__ Wt,
    const float* __restrict__ bfv, const float* __restrict__ biv,
    const float* __restrict__ bov, const float* __restrict__ bgv,
    float* __restrict__ cbuf, float* __restrict__ outp, int t) {
  // pad rows to 136 bf16 (272B = 17*16B): 16B-aligned frag loads, banks shift
  // by 4 dwords per row -> ~2-way (free) conflicts on frag reads.
  __shared__ __hip_bfloat16 zs[64][136];   // z chunk  [b][kk]
  __shared__ __hip_bfloat16 wsm[32][136];  // W chunk  [col][kk]
  __shared__ float gs[64][36];             // gate tile for reduction/pointwise

  const int tid = threadIdx.x;
  const int lane = tid & 63, w = tid >> 6;
  const int quad = lane >> 4, hc = lane & 15;
  const int l0 = blockIdx.x * 8;

  f32x4 acc[4][2] = {};  // 4 b-tiles x 2 c-tiles, full 64x32 block tile per wave

  // z staging map: thread -> (row b, 32-col segment)
  const int zr = tid >> 2;
  const int zc = (tid & 3) * 32;
  // W staging map: thread -> (block col j, 16-elem segment)
  const int wj = tid >> 3;
  const int ws8 = (tid & 7) * 16;
  const int wC = ((wj >> 3) << 10) + l0 + (wj & 7);  // global weight col
  const __hip_bfloat16* wrow = Wt + ((size_t)wC << 11);

  const int kw = w * 32 + quad * 8;  // this wave's k-offset within a chunk

  for (int ch = 0; ch < 16; ++ch) {
    const int kc = ch << 7;  // chunk base k (contiguous 128)
    // ---- stage z = [x_t | h_{t-1}] as bf16 ----
    if (kc < DD) {
      const float* src = x + (((size_t)t * BB + zr) << 10) + kc + zc;
#pragma unroll
      for (int i = 0; i < 8; ++i) {
        const float4 v = *(const float4*)(src + i * 4);
        zs[zr][zc + i * 4 + 0] = __float2bfloat16(v.x);
        zs[zr][zc + i * 4 + 1] = __float2bfloat16(v.y);
        zs[zr][zc + i * 4 + 2] = __float2bfloat16(v.z);
        zs[zr][zc + i * 4 + 3] = __float2bfloat16(v.w);
      }
    } else if (t > 0) {
      const float* src = outp + (((size_t)(t - 1) * BB + zr) << 10) + (kc - DD) + zc;
#pragma unroll
      for (int i = 0; i < 8; ++i) {
        const float4 v = *(const float4*)(src + i * 4);
        zs[zr][zc + i * 4 + 0] = __float2bfloat16(v.x);
        zs[zr][zc + i * 4 + 1] = __float2bfloat16(v.y);
        zs[zr][zc + i * 4 + 2] = __float2bfloat16(v.z);
        zs[zr][zc + i * 4 + 3] = __float2bfloat16(v.w);
      }
    } else {  // t==0: h_{-1} = 0
      const __hip_bfloat16 z0 = __float2bfloat16(0.0f);
#pragma unroll
      for (int i = 0; i < 8; ++i) {
        zs[zr][zc + i * 4 + 0] = z0;
        zs[zr][zc + i * 4 + 1] = z0;
        zs[zr][zc + i * 4 + 2] = z0;
        zs[zr][zc + i * 4 + 3] = z0;
      }
    }
    // ---- stage W (already bf16, k-contiguous): 2x 16B per thread ----
    {
      const uint4* s = (const uint4*)(wrow + kc + ws8);
      const uint4 v0 = s[0], v1 = s[1];
      *(uint4*)&wsm[wj][ws8] = v0;
      *(uint4*)&wsm[wj][ws8 + 8] = v1;
    }
    __syncthreads();
    // ---- MFMA: wave w consumes k-slice [kw, kw+32) of this chunk ----
    {
      const short8 a0 = *(const short8*)&zs[0 * 16 + hc][kw];
      const short8 a1 = *(const short8*)&zs[1 * 16 + hc][kw];
      const short8 a2 = *(const short8*)&zs[2 * 16 + hc][kw];
      const short8 a3 = *(const short8*)&zs[3 * 16 + hc][kw];
      const short8 b0 = *(const short8*)&wsm[0 * 16 + hc][kw];
      const short8 b1 = *(const short8*)&wsm[1 * 16 + hc][kw];
      acc[0][0] = __builtin_amdgcn_mfma_f32_16x16x32_bf16(a0, b0, acc[0][0], 0, 0, 0);
      acc[1][0] = __builtin_amdgcn_mfma_f32_16x16x32_bf16(a1, b0, acc[1][0], 0, 0, 0);
      acc[2][0] = __builtin_amdgcn_mfma_f32_16x16x32_bf16(a2, b0, acc[2][0], 0, 0, 0);
      acc[3][0] = __builtin_amdgcn_mfma_f32_16x16x32_bf16(a3, b0, acc[3][0], 0, 0, 0);
      acc[0][1] = __builtin_amdgcn_mfma_f32_16x16x32_bf16(a0, b1, acc[0][1], 0, 0, 0);
      acc[1][1] = __builtin_amdgcn_mfma_f32_16x16x32_bf16(a1, b1, acc[1][1], 0, 0, 0);
      acc[2][1] = __builtin_amdgcn_mfma_f32_16x16x32_bf16(a2, b1, acc[2][1], 0, 0, 0);
      acc[3][1] = __builtin_amdgcn_mfma_f32_16x16x32_bf16(a3, b1, acc[3][1], 0, 0, 0);
    }
    __syncthreads();
  }

  // ---- cross-wave K-slice reduction into gs ----
  for (int p = 0; p < 4; ++p) {
    if (w == p) {
#pragma unroll
      for (int bt = 0; bt < 4; ++bt)
#pragma unroll
        for (int ct = 0; ct < 2; ++ct)
#pragma unroll
          for (int r = 0; r < 4; ++r) {
            float* dst = &gs[bt * 16 + quad * 4 + r][ct * 16 + hc];
            if (p == 0) *dst = acc[bt][ct][r];
            else        *dst += acc[bt][ct][r];
          }
    }
    __syncthreads();
  }

  // ---- pointwise LSTM update (fp32). col j in gs: gate g = j>>3, li = j&7 ----
  for (int p = tid; p < 512; p += 256) {
    const int b = p >> 3, li = p & 7;
    const int l = l0 + li;
    const float fp = gs[b][0 * 8 + li] + bfv[l];
    const float ip = gs[b][1 * 8 + li] + biv[l];
    const float op = gs[b][2 * 8 + li] + bov[l];
    const float gp = gs[b][3 * 8 + li] + bgv[l];
    const float fs = 1.0f / (1.0f + __expf(-fp));
    const float is = 1.0f / (1.0f + __expf(-ip));
    const float os = 1.0f / (1.0f + __expf(-op));
    const float gv = tanhf(gp);
    const size_t ci = ((size_t)b << 10) + l;
    const float cn = fs * cbuf[ci] + is * gv;
    cbuf[ci] = cn;
    outp[(((size_t)t * BB + b) << 10) + l] = os * tanhf(cn);
  }
}

// ---------------------------------------------------------------------------
extern "C" void kernel_launch(void* const* d_in, const int* in_sizes, int n_in,
                              void* d_out, int out_size, void* d_ws, size_t ws_size,
                              hipStream_t stream) {
  const float* x   = (const float*)d_in[0];
  const float* Wf  = (const float*)d_in[1];
  const float* bfv = (const float*)d_in[2];
  const float* Wi  = (const float*)d_in[3];
  const float* biv = (const float*)d_in[4];
  const float* Wo  = (const float*)d_in[5];
  const float* bov = (const float*)d_in[6];
  const float* Wg  = (const float*)d_in[7];
  const float* bgv = (const float*)d_in[8];
  float* out = (float*)d_out;

  // ws layout: Wt bf16 [4096][2048] (16 MiB) | c state fp32 [64][1024] (256 KiB)
  __hip_bfloat16* Wt = (__hip_bfloat16*)d_ws;
  float* cbuf = (float*)((char*)d_ws + (size_t)4096 * 2048 * sizeof(__hip_bfloat16));

  transpose_w<<<dim3(64, 32, 4), 256, 0, stream>>>(Wf, Wi, Wo, Wg, Wt);
  hipMemsetAsync(cbuf, 0, (size_t)BB * LL * sizeof(float), stream);

  for (int t = 0; t < TT; ++t) {
    lstm_step<<<128, 256, 0, stream>>>(x, Wt, bfv, biv, bov, bgv, cbuf, out, t);
  }
}